// Round 16
// baseline (260.862 us; speedup 1.0000x reference)
//
#include <hip/hip_runtime.h>

#define B_   2
#define T_   2048
#define C_   768
#define H_   12
#define HD_  64
#define M_   (B_ * T_)    // 4096 rows
#define N3_  (3 * C_)     // 2304
#define KB_  (C_ * 2)     // 1536 bytes per row (bf16)

typedef __bf16 bf16_t;
typedef bf16_t bf16x8 __attribute__((ext_vector_type(8)));
typedef float  floatx4 __attribute__((ext_vector_type(4)));
typedef unsigned long long u64_t;

__device__ inline floatx4 mfma_bf16(bf16x8 a, bf16x8 b, floatx4 c) {
    return __builtin_amdgcn_mfma_f32_16x16x32_bf16(a, b, c, 0, 0, 0);
}

__device__ __forceinline__ void async_copy16(const void* g, void* l) {
    __builtin_amdgcn_global_load_lds(
        (const __attribute__((address_space(1))) void*)g,
        (__attribute__((address_space(3))) void*)l, 16, 0, 0);
}

__device__ __forceinline__ bf16x8 frag_read(const char* ldsbase, int row, int quad) {
    int slot = quad ^ ((row >> 1) & 3);
    return *(const bf16x8*)(ldsbase + row * 64 + slot * 16);
}

// ---------------------------------------------------------------------------
// 128x128-tile GEMM mainloop, DOUBLE-BUFFERED, 512 THREADS (8 waves).
// Best-measured GEMM shape (round-14 anchor, 249.7us total).
// ---------------------------------------------------------------------------
template<bool TRIPLE>
__device__ __forceinline__ void gemm_loop8(
    const char* Ah, const char* Al, const char* Bh, const char* Bl,
    char* lds, floatx4 (&acc)[4][2])
{
    int tid = threadIdx.x, lane = tid & 63, wave = tid >> 6;
    int l15 = lane & 15, quad = lane >> 4;
    int wr = wave >> 2, wc = wave & 3;
    const int PH = TRIPLE ? 32768 : 16384;
    auto stage1 = [&](const char* tile, char* base, int k0) {
        int p = tid;                             // 512 x 16B = 8 KB
        int r = p >> 2, slot = p & 3;
        int g = slot ^ ((r >> 1) & 3);
        async_copy16(tile + (size_t)r * KB_ + k0 + g * 16, base + p * 16);
    };
    auto stage = [&](int ph, int k0) {
        char* base = lds + ph * PH;
        stage1(Ah, base, k0);
        stage1(Bh, base + 8192, k0);
        if (TRIPLE) {
            stage1(Al, base + 16384, k0);
            stage1(Bl, base + 24576, k0);
        }
    };
    stage(0, 0);
    int ph = 0;
#pragma unroll 1
    for (int k0 = 0; k0 < KB_; k0 += 64) {       // 32 bf16 per chunk
        __syncthreads();                          // drains stage(ph)
        if (k0 + 64 < KB_) stage(ph ^ 1, k0 + 64);
        char* base = lds + ph * PH;
        bf16x8 ah[4], al[4], bh[2], bl[2];
#pragma unroll
        for (int t = 0; t < 4; ++t) {
            ah[t] = frag_read(base, wr * 64 + t * 16 + l15, quad);
            if (TRIPLE)
                al[t] = frag_read(base + 16384, wr * 64 + t * 16 + l15, quad);
        }
#pragma unroll
        for (int t = 0; t < 2; ++t) {
            bh[t] = frag_read(base + 8192, wc * 32 + t * 16 + l15, quad);
            if (TRIPLE)
                bl[t] = frag_read(base + 24576, wc * 32 + t * 16 + l15, quad);
        }
#pragma unroll
        for (int mi = 0; mi < 4; ++mi)
#pragma unroll
            for (int ni = 0; ni < 2; ++ni) {
                acc[mi][ni] = mfma_bf16(ah[mi], bh[ni], acc[mi][ni]);
                if (TRIPLE) {
                    acc[mi][ni] = mfma_bf16(ah[mi], bl[ni], acc[mi][ni]);
                    acc[mi][ni] = mfma_bf16(al[mi], bh[ni], acc[mi][ni]);
                }
            }
        ph ^= 1;
    }
}

// ---------------------------------------------------------------------------
// K0 (v2): VECTORIZED prep — float4 loads, packed 8B bf16x4 stores.
// ---------------------------------------------------------------------------
__global__ __launch_bounds__(256) void prep_kernel(
    const float* __restrict__ x, const float* __restrict__ w_attn,
    const float* __restrict__ w_proj,
    bf16_t* __restrict__ x_hi, bf16_t* __restrict__ x_lo,
    bf16_t* __restrict__ w_hi, bf16_t* __restrict__ w_lo,
    bf16_t* __restrict__ wp_b, int nx4, int nw4, int np4)
{
    int g4 = blockIdx.x * 256 + threadIdx.x;
    union U { bf16_t e[4]; u64_t v; };
    if (g4 < nx4) {
        float4 f = ((const float4*)x)[g4];
        U h, l;
        h.e[0] = (bf16_t)f.x; l.e[0] = (bf16_t)(f.x - (float)h.e[0]);
        h.e[1] = (bf16_t)f.y; l.e[1] = (bf16_t)(f.y - (float)h.e[1]);
        h.e[2] = (bf16_t)f.z; l.e[2] = (bf16_t)(f.z - (float)h.e[2]);
        h.e[3] = (bf16_t)f.w; l.e[3] = (bf16_t)(f.w - (float)h.e[3]);
        ((u64_t*)x_hi)[g4] = h.v;
        ((u64_t*)x_lo)[g4] = l.v;
    } else if (g4 < nx4 + nw4) {
        int i = g4 - nx4;
        float4 f = ((const float4*)w_attn)[i];
        U h, l;
        h.e[0] = (bf16_t)f.x; l.e[0] = (bf16_t)(f.x - (float)h.e[0]);
        h.e[1] = (bf16_t)f.y; l.e[1] = (bf16_t)(f.y - (float)h.e[1]);
        h.e[2] = (bf16_t)f.z; l.e[2] = (bf16_t)(f.z - (float)h.e[2]);
        h.e[3] = (bf16_t)f.w; l.e[3] = (bf16_t)(f.w - (float)h.e[3]);
        ((u64_t*)w_hi)[i] = h.v;
        ((u64_t*)w_lo)[i] = l.v;
    } else if (g4 < nx4 + nw4 + np4) {
        int i = g4 - nx4 - nw4;
        float4 f = ((const float4*)w_proj)[i];
        U h;
        h.e[0] = (bf16_t)f.x;
        h.e[1] = (bf16_t)f.y;
        h.e[2] = (bf16_t)f.z;
        h.e[3] = (bf16_t)f.w;
        ((u64_t*)wp_b)[i] = h.v;
    }
}

// ---------------------------------------------------------------------------
// K1 (v18): qkv = x @ w_attn^T + b_attn (512 threads).  q/k bf16x3.
// V-FUSION: v-region blocks transpose in-LDS and write vt directly.
// ---------------------------------------------------------------------------
__global__ __launch_bounds__(512) void qkv_gemm(
    const bf16_t* __restrict__ x_hi, const bf16_t* __restrict__ x_lo,
    const bf16_t* __restrict__ w_hi, const bf16_t* __restrict__ w_lo,
    const float* __restrict__ bias, const float* __restrict__ selw,
    bf16_t* __restrict__ q_hi, bf16_t* __restrict__ q_lo,
    bf16_t* __restrict__ kw_hi, bf16_t* __restrict__ kw_lo,
    bf16_t* __restrict__ k_b, bf16_t* __restrict__ vt)
{
    extern __shared__ char lds[];
    int m0 = blockIdx.x * 128, n0 = blockIdx.y * 128;
    floatx4 acc[4][2];
#pragma unroll
    for (int i = 0; i < 4; ++i)
#pragma unroll
        for (int j = 0; j < 2; ++j) acc[i][j] = (floatx4){0.f, 0.f, 0.f, 0.f};
    if (n0 >= 2 * C_) {
        gemm_loop8<false>((const char*)(x_hi + (size_t)m0 * C_), nullptr,
                          (const char*)(w_hi + (size_t)n0 * C_), nullptr, lds, acc);
    } else {
        gemm_loop8<true>((const char*)(x_hi + (size_t)m0 * C_),
                         (const char*)(x_lo + (size_t)m0 * C_),
                         (const char*)(w_hi + (size_t)n0 * C_),
                         (const char*)(w_lo + (size_t)n0 * C_), lds, acc);
    }

    int tid = threadIdx.x, lane = tid & 63, wave = tid >> 6;
    int l15 = lane & 15, quad = lane >> 4;
    int wr = wave >> 2, wc = wave & 3;

    if (n0 >= 2 * C_) {
        // ---- V path: in-LDS transpose, direct vt write ----
        __syncthreads();                      // staging buffers now dead
        bf16_t* TL = (bf16_t*)lds;            // [128 cols][136] bf16 = 34.8 KB
#pragma unroll
        for (int ni = 0; ni < 2; ++ni) {
            int colp = wc * 32 + ni * 16 + l15;       // 0..127
            float bb = bias[n0 + colp];
#pragma unroll
            for (int mi = 0; mi < 4; ++mi)
#pragma unroll
                for (int r = 0; r < 4; ++r) {
                    int rowp = wr * 64 + mi * 16 + quad * 4 + r;
                    TL[colp * 136 + rowp] = (bf16_t)(acc[mi][ni][r] + bb);
                }
        }
        __syncthreads();
        int colp = tid >> 2, sub = tid & 3;
        int cg = n0 - 2 * C_ + colp;          // 0..767
        int h  = cg >> 6, hd = cg & 63;
        int bb = m0 >> 11;                    // batch (m0 is 128-aligned)
        int t0 = m0 - bb * T_;
        bf16_t* dst = vt + (((size_t)(bb * H_ + h) * HD_ + hd) * T_) + t0 + sub * 32;
        const bf16_t* srcl = TL + colp * 136 + sub * 32;
#pragma unroll
        for (int k = 0; k < 4; ++k)
            *(int4*)(dst + k * 8) = *(const int4*)(srcl + k * 8);
        return;
    }

    // ---- q/k path ----
    int cb = n0 + wc * 32;
#pragma unroll
    for (int ni = 0; ni < 2; ++ni) {
        int col = cb + ni * 16 + l15;
        float bb = bias[col];
#pragma unroll
        for (int mi = 0; mi < 4; ++mi)
#pragma unroll
            for (int r = 0; r < 4; ++r) {
                int row = m0 + wr * 64 + mi * 16 + quad * 4 + r;
                float v = acc[mi][ni][r] + bb;
                if (cb < C_) {
                    float vs = v * 0.125f;
                    bf16_t h = (bf16_t)vs;
                    q_hi[(size_t)row * C_ + col] = h;
                    q_lo[(size_t)row * C_ + col] = (bf16_t)(vs - (float)h);
                } else {
                    int c2 = col - C_;
                    k_b[(size_t)row * C_ + c2] = (bf16_t)v;
                    float kw = v * selw[c2 >> 6];
                    bf16_t h = (bf16_t)kw;
                    kw_hi[(size_t)row * C_ + c2] = h;
                    kw_lo[(size_t)row * C_ + c2] = (bf16_t)(kw - (float)h);
                }
            }
    }
}

// ---------------------------------------------------------------------------
// K2: triangular s_gemm (512 threads), fused segsum.
// ---------------------------------------------------------------------------
#define SEG_    16
#define SEGLEN_ (T_ / SEG_)  // 128

__global__ __launch_bounds__(512) void s_gemm(
    const bf16_t* __restrict__ q_hi, const bf16_t* __restrict__ q_lo,
    const bf16_t* __restrict__ kw_hi, const bf16_t* __restrict__ kw_lo,
    float* __restrict__ SF, float* __restrict__ segsum)
{
    extern __shared__ char lds[];
    int t = blockIdx.x, b = blockIdx.z;
    int it = (int)((sqrtf(8.f * t + 1.f) - 1.f) * 0.5f);
    while ((it + 1) * (it + 2) / 2 <= t) ++it;
    while (it * (it + 1) / 2 > t) --it;
    int jt = t - it * (it + 1) / 2;               // jt <= it
    int i0 = it * 128, j0 = jt * 128;
    float* out = SF + (size_t)b * T_ * T_;

    floatx4 acc[4][2];
#pragma unroll
    for (int i = 0; i < 4; ++i)
#pragma unroll
        for (int j = 0; j < 2; ++j) acc[i][j] = (floatx4){0.f, 0.f, 0.f, 0.f};
    size_t arow = ((size_t)b * T_ + i0) * C_;
    size_t brow = ((size_t)b * T_ + j0) * C_;
    gemm_loop8<true>((const char*)(q_hi + arow), (const char*)(q_lo + arow),
                     (const char*)(kw_hi + brow), (const char*)(kw_lo + brow),
                     lds, acc);

    int tid = threadIdx.x, lane = tid & 63, wave = tid >> 6;
    int l15 = lane & 15, quad = lane >> 4;
    int wr = wave >> 2, wc = wave & 3;
    float colsum[2] = {0.f, 0.f};
#pragma unroll
    for (int ni = 0; ni < 2; ++ni) {
        int j = j0 + wc * 32 + ni * 16 + l15;
#pragma unroll
        for (int mi = 0; mi < 4; ++mi)
#pragma unroll
            for (int r = 0; r < 4; ++r) {
                int i = i0 + wr * 64 + mi * 16 + quad * 4 + r;
                float s = acc[mi][ni][r];
                s = (j >= 1 && j < i) ? fmaxf(s, 0.f) : 0.f;
                out[(size_t)i * T_ + j] = s;
                colsum[ni] += s;
            }
    }
#pragma unroll
    for (int ni = 0; ni < 2; ++ni) {
        colsum[ni] += __shfl_xor(colsum[ni], 16);
        colsum[ni] += __shfl_xor(colsum[ni], 32);
    }
    float* red = (float*)lds;                     // [wr][128] (phase-0 area)
    if (quad == 0) {
#pragma unroll
        for (int ni = 0; ni < 2; ++ni)
            red[wr * 128 + wc * 32 + ni * 16 + l15] = colsum[ni];
    }
    __syncthreads();
    if (tid < 128) {
        float ssum = red[tid] + red[128 + tid];
        segsum[((size_t)b * SEG_ + it) * T_ + j0 + tid] = ssum;
    }
}

// ---------------------------------------------------------------------------
// K4: scan_apply with inline exclusive segment prefix from raw segsum.
// ---------------------------------------------------------------------------
__global__ __launch_bounds__(256) void scan_apply(
    float* __restrict__ SF, const float* __restrict__ segsum)
{
    int gid  = blockIdx.x * 256 + threadIdx.x;
    int j    = gid & (T_ - 1);
    int rest = gid >> 11;
    int seg  = rest & (SEG_ - 1);
    int b    = rest >> 4;
    if (seg * SEGLEN_ + SEGLEN_ - 1 < j) return;
    float run = 0.f;
    for (int s = 0; s < seg; ++s) {
        float v = (s * SEGLEN_ + SEGLEN_ - 1 <= j) ? 0.f
                : segsum[((size_t)b * SEG_ + s) * T_ + j];
        run += v;
    }
    float* col = SF + (size_t)b * T_ * T_ + (size_t)(seg * SEGLEN_) * T_ + j;
#pragma unroll 4
    for (int i = 0; i < SEGLEN_; ++i) {
        float s = col[(size_t)i * T_];
        s = (seg * SEGLEN_ + i > j) ? s : 0.f;
        col[(size_t)i * T_] = run;
        run += s;
    }
}

// ---------------------------------------------------------------------------
// K6 (v19): TWO-HEAD flash attention, KVBLK=64.
// Round-28 theory: all eight attn variants ride ~7.6 TB/s of L2/L3-level
// traffic (v8-v14: ~420MB/55us; v13: ~1GB/132us — same rate) -> the kernel
// is L2/L3-traffic-bound, which is why every structural probe was null.
// Biggest reducible component: FF logical reads (200MB; 12 heads re-read
// identical FF[i][j]).  Each block now processes heads (y, y+6) over the
// same (i,j) range: ff registers loaded ONCE per iteration feed both heads'
// exp.  LDS: KL 2ph x 2h x 8KB + VL same + PB 8KB = 72KB -> 2 blocks/CU
// (8 waves/CU, same as v11 -- no occupancy regression).  PB reused
// sequentially between heads (wave-private, DS in-order: safe).
// Grid 48 x 6 x 2.  Traffic 420 -> ~320MB.
// ---------------------------------------------------------------------------
__global__ __launch_bounds__(256) void attn_kernel(
    const bf16_t* __restrict__ q_b, const bf16_t* __restrict__ k_b,
    const bf16_t* __restrict__ vt_g, const float* __restrict__ FF,
    bf16_t* __restrict__ y_b, float* __restrict__ opart,
    float* __restrict__ lpart)
{
    __shared__ __align__(16) char KL[2][2][8192];   // [ph][head]
    __shared__ __align__(16) char VL[2][2][8192];
    __shared__ __align__(16) bf16_t PB[4][1024];    // per-wave P [16][64]

    int tid = threadIdx.x, lane = tid & 63, wave = tid >> 6;
    int l15 = lane & 15, quad = lane >> 4;
    int u = blockIdx.x & 15, g = blockIdx.x >> 4;
    int tile, jlo, jhi, half;
    bool split;
    if (g == 0)      { tile = 16 + u; jlo = 0;  jhi = 15;       half = 0; split = true;  }
    else if (g == 1) { tile = u;      jlo = 0;  jhi = u;        half = 0; split = false; }
    else             { tile = 31 - u; jlo = 16; jhi = 31 - u;   half = 1; split = true;  }
    int h0 = blockIdx.y, h1 = blockIdx.y + 6, b = blockIdx.z;
    int i0w = tile * 64 + wave * 16;
    const floatx4 fzero = {0.f, 0.f, 0.f, 0.f};

    const bf16_t* qr0 = q_b + ((size_t)b * T_ + i0w + l15) * C_ + h0 * HD_;
    const bf16_t* qr1 = q_b + ((size_t)b * T_ + i0w + l15) * C_ + h1 * HD_;
    bf16x8 qa0_0 = *(const bf16x8*)(qr0 + quad * 8);
    bf16x8 qa1_0 = *(const bf16x8*)(qr0 + 32 + quad * 8);
    bf16x8 qa0_1 = *(const bf16x8*)(qr1 + quad * 8);
    bf16x8 qa1_1 = *(const bf16x8*)(qr1 + 32 + quad * 8);

    const bf16_t* kb0 = k_b + (size_t)b * T_ * C_ + h0 * HD_;
    const bf16_t* kb1 = k_b + (size_t)b * T_ * C_ + h1 * HD_;
    const bf16_t* vb0 = vt_g + (size_t)(b * H_ + h0) * HD_ * T_;
    const bf16_t* vb1 = vt_g + (size_t)(b * H_ + h1) * HD_ * T_;

    // C-layout FF row pointers: row = i0w + quad*4 + r, col = j + l15
    const float* fpr[4];
#pragma unroll
    for (int r = 0; r < 4; ++r)
        fpr[r] = FF + ((size_t)b * T_ + i0w + quad * 4 + r) * T_ + jlo * 64 + l15;

    auto stage = [&](int ph, int j0) {
#pragma unroll
        for (int i = 0; i < 2; ++i) {
            int p = (wave * 2 + i) * 64 + lane;
            int r = p >> 3, sp = p & 7, s = sp ^ (r & 7);
            async_copy16(kb0 + (size_t)(j0 + r) * C_ + s * 8, &KL[ph][0][p * 16]);
            async_copy16(kb1 + (size_t)(j0 + r) * C_ + s * 8, &KL[ph][1][p * 16]);
            async_copy16(vb0 + (size_t)r * T_ + j0 + s * 8, &VL[ph][0][p * 16]);
            async_copy16(vb1 + (size_t)r * T_ + j0 + s * 8, &VL[ph][1][p * 16]);
        }
    };

    float l0[4] = {0.f, 0.f, 0.f, 0.f}, l1[4] = {0.f, 0.f, 0.f, 0.f};
    floatx4 O0[4], O1[4];
#pragma unroll
    for (int nt = 0; nt < 4; ++nt) { O0[nt] = fzero; O1[nt] = fzero; }

    stage(0, jlo * 64);
    int ph = 0;
#pragma unroll 1
    for (int jc = jlo; jc <= jhi; ++jc) {
        __syncthreads();
        if (jc < jhi) stage(ph ^ 1, (jc + 1) * 64);

        // FF C-layout: 16 dword loads, shared by BOTH heads
        float ff[4][4];
#pragma unroll
        for (int r = 0; r < 4; ++r) {
#pragma unroll
            for (int s = 0; s < 4; ++s) ff[s][r] = fpr[r][s * 16];
            fpr[r] += 64;
        }
        bool diag = (jc * 64 + 63 > i0w);

        auto do_head = [&](const char* KLh, const char* VLh,
                           bf16x8 qa0, bf16x8 qa1,
                           floatx4 (&O)[4], float (&l_lane)[4]) {
            // QK^T -> C-layout
            floatx4 pc[4];
#pragma unroll
            for (int s = 0; s < 4; ++s) {
                int r = s * 16 + l15;
                bf16x8 k0 = *(const bf16x8*)&KLh[r * 128 + ((quad     ^ (r & 7)) * 16)];
                bf16x8 k1 = *(const bf16x8*)&KLh[r * 128 + (((quad+4) ^ (r & 7)) * 16)];
                floatx4 p = mfma_bf16(qa0, k0, fzero);
                pc[s] = mfma_bf16(qa1, k1, p);
            }
            float p[4][4];
#pragma unroll
            for (int s = 0; s < 4; ++s)
#pragma unroll
                for (int r = 0; r < 4; ++r) {
                    float lg = pc[s][r] - ff[s][r] - 20.f;
                    if (diag) {
                        int i = i0w + quad * 4 + r;
                        int j = jc * 64 + s * 16 + l15;
                        lg = (j <= i) ? lg : -__builtin_inff();
                    }
                    p[s][r] = __expf(lg);
                }
#pragma unroll
            for (int r = 0; r < 4; ++r)
                l_lane[r] += (p[0][r] + p[1][r]) + (p[2][r] + p[3][r]);

            // P: C-layout -> bf16 LDS (16B-chunk XOR swizzle) -> A-frags
            bf16_t* Pw = PB[wave];
#pragma unroll
            for (int s = 0; s < 4; ++s)
#pragma unroll
                for (int r = 0; r < 4; ++r) {
                    int rr = quad * 4 + r;
                    int ch = (s * 2 + (l15 >> 3)) ^ (rr & 7);
                    Pw[rr * 64 + ch * 8 + (l15 & 7)] = (bf16_t)p[s][r];
                }
            asm volatile("s_waitcnt lgkmcnt(0)" ::: "memory");
            int xk = l15 & 7;
            bf16x8 pa0 = *(const bf16x8*)&Pw[l15 * 64 + ((quad ^ xk) * 8)];
            bf16x8 pa1 = *(const bf16x8*)&Pw[l15 * 64 + (((4 + quad) ^ xk) * 8)];
#pragma unroll
            for (int nt = 0; nt < 4; ++nt) {
                int rv = nt * 16 + l15;
                bf16x8 v0 = *(const bf16x8*)&VLh[rv * 128 + ((quad     ^ (rv & 7)) * 16)];
                bf16x8 v1 = *(const bf16x8*)&VLh[rv * 128 + (((quad+4) ^ (rv & 7)) * 16)];
                O[nt] = mfma_bf16(pa0, v0, O[nt]);
                O[nt] = mfma_bf16(pa1, v1, O[nt]);
            }
        };
        do_head(&KL[ph][0][0], &VL[ph][0][0], qa0_0, qa1_0, O0, l0);
        do_head(&KL[ph][1][0], &VL[ph][1][0], qa0_1, qa1_1, O1, l1);
        ph ^= 1;
    }

    auto fin = [&](floatx4 (&O)[4], float (&l_lane)[4], int h) {
#pragma unroll
        for (int r = 0; r < 4; ++r)
#pragma unroll
            for (int d = 1; d < 16; d <<= 1)
                l_lane[r] += __shfl_xor(l_lane[r], d);
        if (!split) {
#pragma unroll
            for (int r = 0; r < 4; ++r) {
                float inv = 1.f / l_lane[r];
                int i = i0w + quad * 4 + r;
#pragma unroll
                for (int nt = 0; nt < 4; ++nt)
                    y_b[((size_t)b * T_ + i) * C_ + h * HD_ + nt * 16 + l15] =
                        (bf16_t)(O[nt][r] * inv);
            }
        } else {
            size_t ob = ((((size_t)(b * H_ + h) * 16 + (tile - 16)) * 2 + half) * 4096);
#pragma unroll
            for (int r = 0; r < 4; ++r) {
                int rl = wave * 16 + quad * 4 + r;
#pragma unroll
                for (int nt = 0; nt < 4; ++nt)
                    opart[ob + (size_t)rl * 64 + nt * 16 + l15] = O[nt][r];
            }
            if (l15 == 0) {
                size_t lb = (((size_t)(b * H_ + h) * 16 + (tile - 16)) * 2 + half) * 64;
#pragma unroll
                for (int r = 0; r < 4; ++r)
                    lpart[lb + wave * 16 + quad * 4 + r] = l_lane[r];
            }
        }
    };
    fin(O0, l0, h0);
    fin(O1, l1, h1);
}

// ---------------------------------------------------------------------------
// K6b: merge split-tile partials: y = (O0+O1)/(l0+l1).
// ---------------------------------------------------------------------------
__global__ __launch_bounds__(256) void merge_kernel(
    const float* __restrict__ opart, const float* __restrict__ lpart,
    bf16_t* __restrict__ y_b)
{
    int tt = blockIdx.x, h = blockIdx.y, b = blockIdx.z;
    size_t b0 = (((size_t)(b * H_ + h) * 16 + tt) * 2) * 4096;
    size_t l0 = (((size_t)(b * H_ + h) * 16 + tt) * 2) * 64;
    int tile = 16 + tt;
#pragma unroll 4
    for (int e = threadIdx.x; e < 4096; e += 256) {
        int row = e >> 6, col = e & 63;
        float l = lpart[l0 + row] + lpart[l0 + 64 + row];
        float o = opart[b0 + e] + opart[b0 + 4096 + e];
        y_b[((size_t)b * T_ + tile * 64 + row) * C_ + h * HD_ + col] =
            (bf16_t)(o / l);
    }
}

// ---------------------------------------------------------------------------
// K7: out = y @ w_proj^T + b_proj  (512 threads, dbuf 32 KB)
// ---------------------------------------------------------------------------
__global__ __launch_bounds__(512) void proj_gemm(
    const bf16_t* __restrict__ y_b, const bf16_t* __restrict__ wp_b,
    const float* __restrict__ bias, float* __restrict__ out)
{
    extern __shared__ char lds[];
    int m0 = blockIdx.x * 128, n0 = blockIdx.y * 128;
    floatx4 acc[4][2];
#pragma unroll
    for (int i = 0; i < 4; ++i)
#pragma unroll
        for (int j = 0; j < 2; ++j) acc[i][j] = (floatx4){0.f, 0.f, 0.f, 0.f};
    gemm_loop8<false>((const char*)(y_b + (size_t)m0 * C_), nullptr,
                      (const char*)(wp_b + (size_t)n0 * C_), nullptr, lds, acc);

    int tid = threadIdx.x, lane = tid & 63, wave = tid >> 6;
    int l15 = lane & 15, quad = lane >> 4;
    int wr = wave >> 2, wc = wave & 3;
#pragma unroll
    for (int ni = 0; ni < 2; ++ni) {
        int col = n0 + wc * 32 + ni * 16 + l15;
        float bb = bias[col];
#pragma unroll
        for (int mi = 0; mi < 4; ++mi)
#pragma unroll
            for (int r = 0; r < 4; ++r)
                out[(size_t)(m0 + wr * 64 + mi * 16 + quad * 4 + r) * C_ + col] =
                    acc[mi][ni][r] + bb;
    }
}

// ---------------------------------------------------------------------------
extern "C" void kernel_launch(void* const* d_in, const int* in_sizes, int n_in,
                              void* d_out, int out_size, void* d_ws, size_t ws_size,
                              hipStream_t stream)
{
    const float* x      = (const float*)d_in[0];
    const float* w_attn = (const float*)d_in[1];
    const float* b_attn = (const float*)d_in[2];
    const float* w_proj = (const float*)d_in[3];
    const float* b_proj = (const float*)d_in[4];
    const float* sel_w  = (const float*)d_in[5];
    float* out = (float*)d_out;

    char* ws = (char*)d_ws;
    size_t off = 0;
    auto alloc = [&](size_t bytes) {
        void* p = ws + off;
        off += (bytes + 255) & ~(size_t)255;
        return p;
    };
    const size_t MC2 = (size_t)M_ * C_ * 2;          // 6.29 MB
    // Live-through-attn region
    bf16_t* q_hi   = (bf16_t*)alloc(MC2);
    bf16_t* kw_hi  = (bf16_t*)alloc(MC2);
    bf16_t* k_b    = (bf16_t*)alloc(MC2);
    bf16_t* y_b    = (bf16_t*)alloc(MC2);
    bf16_t* wp_b   = (bf16_t*)alloc((size_t)C_ * C_ * 2);
    float*  segsum = (float*)alloc((size_t)B_ * SEG_ * T_ * 4);
    float*  lpart  = (float*)alloc((size_t)B_ * H_ * 16 * 2 * 64 * 4);  // 0.2 MB
    // Dead-by-attn group: q_lo, kw_lo aliased by opart; vt disjoint.
    char* dead_base = (char*)alloc(3 * MC2);
    bf16_t* q_lo  = (bf16_t*)dead_base;
    bf16_t* kw_lo = (bf16_t*)(dead_base + MC2);
    bf16_t* vt    = (bf16_t*)(dead_base + 2 * MC2);
    float*  opart = (float*)dead_base;
    // Aliased region: phase-1 splits and SF never live simultaneously
    char* shared_base = (char*)alloc((size_t)B_ * T_ * T_ * 4);   // 33.55 MB
    bf16_t* x_hi = (bf16_t*)shared_base;
    bf16_t* x_lo = (bf16_t*)(shared_base + MC2);
    bf16_t* w_hi = (bf16_t*)(shared_base + 2 * MC2);
    bf16_t* w_lo = (bf16_t*)(shared_base + 2 * MC2 + (size_t)N3_ * C_ * 2);
    float*  SF   = (float*)shared_base;

    int nx = M_ * C_, nw = N3_ * C_, np = C_ * C_;
    int ntot4 = (nx + nw + np) / 4;
    prep_kernel<<<dim3((ntot4 + 255) / 256), 256, 0, stream>>>(
        x, w_attn, w_proj, x_hi, x_lo, w_hi, w_lo, wp_b, nx / 4, nw / 4, np / 4);

    qkv_gemm<<<dim3(M_ / 128, N3_ / 128), 512, 65536, stream>>>(
        x_hi, x_lo, w_hi, w_lo, b_attn, sel_w,
        q_hi, q_lo, kw_hi, kw_lo, k_b, vt);
    s_gemm<<<dim3(136, 1, B_), 512, 65536, stream>>>(
        q_hi, q_lo, kw_hi, kw_lo, SF, segsum);
    scan_apply<<<dim3(B_ * SEG_ * T_ / 256), 256, 0, stream>>>(SF, segsum);
    attn_kernel<<<dim3(48, 6, B_), 256, 0, stream>>>(
        q_hi, k_b, vt, SF, y_b, opart, lpart);
    merge_kernel<<<dim3(16, H_, B_), 256, 0, stream>>>(opart, lpart, y_b);
    proj_gemm<<<dim3(M_ / 128, C_ / 128), 512, 32768, stream>>>(y_b, wp_b, b_proj, out);
}

// Round 17
// 248.138 us; speedup vs baseline: 1.0513x; 1.0513x over previous
//
#include <hip/hip_runtime.h>

#define B_   2
#define T_   2048
#define C_   768
#define H_   12
#define HD_  64
#define M_   (B_ * T_)    // 4096 rows
#define N3_  (3 * C_)     // 2304
#define KB_  (C_ * 2)     // 1536 bytes per row (bf16)

typedef __bf16 bf16_t;
typedef bf16_t bf16x8 __attribute__((ext_vector_type(8)));
typedef float  floatx4 __attribute__((ext_vector_type(4)));
typedef unsigned long long u64_t;

__device__ inline floatx4 mfma_bf16(bf16x8 a, bf16x8 b, floatx4 c) {
    return __builtin_amdgcn_mfma_f32_16x16x32_bf16(a, b, c, 0, 0, 0);
}

__device__ __forceinline__ void async_copy16(const void* g, void* l) {
    __builtin_amdgcn_global_load_lds(
        (const __attribute__((address_space(1))) void*)g,
        (__attribute__((address_space(3))) void*)l, 16, 0, 0);
}

__device__ __forceinline__ bf16x8 frag_read(const char* ldsbase, int row, int quad) {
    int slot = quad ^ ((row >> 1) & 3);
    return *(const bf16x8*)(ldsbase + row * 64 + slot * 16);
}

// ---------------------------------------------------------------------------
// 128x128-tile GEMM mainloop, DOUBLE-BUFFERED, 512 THREADS (8 waves).
// Best-measured GEMM shape (round-14 anchor, 249.7us total).
// ---------------------------------------------------------------------------
template<bool TRIPLE>
__device__ __forceinline__ void gemm_loop8(
    const char* Ah, const char* Al, const char* Bh, const char* Bl,
    char* lds, floatx4 (&acc)[4][2])
{
    int tid = threadIdx.x, lane = tid & 63, wave = tid >> 6;
    int l15 = lane & 15, quad = lane >> 4;
    int wr = wave >> 2, wc = wave & 3;
    const int PH = TRIPLE ? 32768 : 16384;
    auto stage1 = [&](const char* tile, char* base, int k0) {
        int p = tid;                             // 512 x 16B = 8 KB
        int r = p >> 2, slot = p & 3;
        int g = slot ^ ((r >> 1) & 3);
        async_copy16(tile + (size_t)r * KB_ + k0 + g * 16, base + p * 16);
    };
    auto stage = [&](int ph, int k0) {
        char* base = lds + ph * PH;
        stage1(Ah, base, k0);
        stage1(Bh, base + 8192, k0);
        if (TRIPLE) {
            stage1(Al, base + 16384, k0);
            stage1(Bl, base + 24576, k0);
        }
    };
    stage(0, 0);
    int ph = 0;
#pragma unroll 1
    for (int k0 = 0; k0 < KB_; k0 += 64) {       // 32 bf16 per chunk
        __syncthreads();                          // drains stage(ph)
        if (k0 + 64 < KB_) stage(ph ^ 1, k0 + 64);
        char* base = lds + ph * PH;
        bf16x8 ah[4], al[4], bh[2], bl[2];
#pragma unroll
        for (int t = 0; t < 4; ++t) {
            ah[t] = frag_read(base, wr * 64 + t * 16 + l15, quad);
            if (TRIPLE)
                al[t] = frag_read(base + 16384, wr * 64 + t * 16 + l15, quad);
        }
#pragma unroll
        for (int t = 0; t < 2; ++t) {
            bh[t] = frag_read(base + 8192, wc * 32 + t * 16 + l15, quad);
            if (TRIPLE)
                bl[t] = frag_read(base + 24576, wc * 32 + t * 16 + l15, quad);
        }
#pragma unroll
        for (int mi = 0; mi < 4; ++mi)
#pragma unroll
            for (int ni = 0; ni < 2; ++ni) {
                acc[mi][ni] = mfma_bf16(ah[mi], bh[ni], acc[mi][ni]);
                if (TRIPLE) {
                    acc[mi][ni] = mfma_bf16(ah[mi], bl[ni], acc[mi][ni]);
                    acc[mi][ni] = mfma_bf16(al[mi], bh[ni], acc[mi][ni]);
                }
            }
        ph ^= 1;
    }
}

// ---------------------------------------------------------------------------
// K0 (v2): VECTORIZED prep — float4 loads, packed 8B bf16x4 stores.
// ---------------------------------------------------------------------------
__global__ __launch_bounds__(256) void prep_kernel(
    const float* __restrict__ x, const float* __restrict__ w_attn,
    const float* __restrict__ w_proj,
    bf16_t* __restrict__ x_hi, bf16_t* __restrict__ x_lo,
    bf16_t* __restrict__ w_hi, bf16_t* __restrict__ w_lo,
    bf16_t* __restrict__ wp_b, int nx4, int nw4, int np4)
{
    int g4 = blockIdx.x * 256 + threadIdx.x;
    union U { bf16_t e[4]; u64_t v; };
    if (g4 < nx4) {
        float4 f = ((const float4*)x)[g4];
        U h, l;
        h.e[0] = (bf16_t)f.x; l.e[0] = (bf16_t)(f.x - (float)h.e[0]);
        h.e[1] = (bf16_t)f.y; l.e[1] = (bf16_t)(f.y - (float)h.e[1]);
        h.e[2] = (bf16_t)f.z; l.e[2] = (bf16_t)(f.z - (float)h.e[2]);
        h.e[3] = (bf16_t)f.w; l.e[3] = (bf16_t)(f.w - (float)h.e[3]);
        ((u64_t*)x_hi)[g4] = h.v;
        ((u64_t*)x_lo)[g4] = l.v;
    } else if (g4 < nx4 + nw4) {
        int i = g4 - nx4;
        float4 f = ((const float4*)w_attn)[i];
        U h, l;
        h.e[0] = (bf16_t)f.x; l.e[0] = (bf16_t)(f.x - (float)h.e[0]);
        h.e[1] = (bf16_t)f.y; l.e[1] = (bf16_t)(f.y - (float)h.e[1]);
        h.e[2] = (bf16_t)f.z; l.e[2] = (bf16_t)(f.z - (float)h.e[2]);
        h.e[3] = (bf16_t)f.w; l.e[3] = (bf16_t)(f.w - (float)h.e[3]);
        ((u64_t*)w_hi)[i] = h.v;
        ((u64_t*)w_lo)[i] = l.v;
    } else if (g4 < nx4 + nw4 + np4) {
        int i = g4 - nx4 - nw4;
        float4 f = ((const float4*)w_proj)[i];
        U h;
        h.e[0] = (bf16_t)f.x;
        h.e[1] = (bf16_t)f.y;
        h.e[2] = (bf16_t)f.z;
        h.e[3] = (bf16_t)f.w;
        ((u64_t*)wp_b)[i] = h.v;
    }
}

// ---------------------------------------------------------------------------
// K1 (v18): qkv = x @ w_attn^T + b_attn (512 threads).  q/k bf16x3.
// V-FUSION: v-region blocks transpose in-LDS and write vt directly.
// ---------------------------------------------------------------------------
__global__ __launch_bounds__(512) void qkv_gemm(
    const bf16_t* __restrict__ x_hi, const bf16_t* __restrict__ x_lo,
    const bf16_t* __restrict__ w_hi, const bf16_t* __restrict__ w_lo,
    const float* __restrict__ bias, const float* __restrict__ selw,
    bf16_t* __restrict__ q_hi, bf16_t* __restrict__ q_lo,
    bf16_t* __restrict__ kw_hi, bf16_t* __restrict__ kw_lo,
    bf16_t* __restrict__ k_b, bf16_t* __restrict__ vt)
{
    extern __shared__ char lds[];
    int m0 = blockIdx.x * 128, n0 = blockIdx.y * 128;
    floatx4 acc[4][2];
#pragma unroll
    for (int i = 0; i < 4; ++i)
#pragma unroll
        for (int j = 0; j < 2; ++j) acc[i][j] = (floatx4){0.f, 0.f, 0.f, 0.f};
    if (n0 >= 2 * C_) {
        gemm_loop8<false>((const char*)(x_hi + (size_t)m0 * C_), nullptr,
                          (const char*)(w_hi + (size_t)n0 * C_), nullptr, lds, acc);
    } else {
        gemm_loop8<true>((const char*)(x_hi + (size_t)m0 * C_),
                         (const char*)(x_lo + (size_t)m0 * C_),
                         (const char*)(w_hi + (size_t)n0 * C_),
                         (const char*)(w_lo + (size_t)n0 * C_), lds, acc);
    }

    int tid = threadIdx.x, lane = tid & 63, wave = tid >> 6;
    int l15 = lane & 15, quad = lane >> 4;
    int wr = wave >> 2, wc = wave & 3;

    if (n0 >= 2 * C_) {
        // ---- V path: in-LDS transpose, direct vt write ----
        __syncthreads();                      // staging buffers now dead
        bf16_t* TL = (bf16_t*)lds;            // [128 cols][136] bf16 = 34.8 KB
#pragma unroll
        for (int ni = 0; ni < 2; ++ni) {
            int colp = wc * 32 + ni * 16 + l15;       // 0..127
            float bb = bias[n0 + colp];
#pragma unroll
            for (int mi = 0; mi < 4; ++mi)
#pragma unroll
                for (int r = 0; r < 4; ++r) {
                    int rowp = wr * 64 + mi * 16 + quad * 4 + r;
                    TL[colp * 136 + rowp] = (bf16_t)(acc[mi][ni][r] + bb);
                }
        }
        __syncthreads();
        int colp = tid >> 2, sub = tid & 3;
        int cg = n0 - 2 * C_ + colp;          // 0..767
        int h  = cg >> 6, hd = cg & 63;
        int bb = m0 >> 11;                    // batch (m0 is 128-aligned)
        int t0 = m0 - bb * T_;
        bf16_t* dst = vt + (((size_t)(bb * H_ + h) * HD_ + hd) * T_) + t0 + sub * 32;
        const bf16_t* srcl = TL + colp * 136 + sub * 32;
#pragma unroll
        for (int k = 0; k < 4; ++k)
            *(int4*)(dst + k * 8) = *(const int4*)(srcl + k * 8);
        return;
    }

    // ---- q/k path ----
    int cb = n0 + wc * 32;
#pragma unroll
    for (int ni = 0; ni < 2; ++ni) {
        int col = cb + ni * 16 + l15;
        float bb = bias[col];
#pragma unroll
        for (int mi = 0; mi < 4; ++mi)
#pragma unroll
            for (int r = 0; r < 4; ++r) {
                int row = m0 + wr * 64 + mi * 16 + quad * 4 + r;
                float v = acc[mi][ni][r] + bb;
                if (cb < C_) {
                    float vs = v * 0.125f;
                    bf16_t h = (bf16_t)vs;
                    q_hi[(size_t)row * C_ + col] = h;
                    q_lo[(size_t)row * C_ + col] = (bf16_t)(vs - (float)h);
                } else {
                    int c2 = col - C_;
                    k_b[(size_t)row * C_ + c2] = (bf16_t)v;
                    float kw = v * selw[c2 >> 6];
                    bf16_t h = (bf16_t)kw;
                    kw_hi[(size_t)row * C_ + c2] = h;
                    kw_lo[(size_t)row * C_ + c2] = (bf16_t)(kw - (float)h);
                }
            }
    }
}

// ---------------------------------------------------------------------------
// K2: triangular s_gemm (512 threads), fused segsum.
// ---------------------------------------------------------------------------
#define SEG_    16
#define SEGLEN_ (T_ / SEG_)  // 128

__global__ __launch_bounds__(512) void s_gemm(
    const bf16_t* __restrict__ q_hi, const bf16_t* __restrict__ q_lo,
    const bf16_t* __restrict__ kw_hi, const bf16_t* __restrict__ kw_lo,
    float* __restrict__ SF, float* __restrict__ segsum)
{
    extern __shared__ char lds[];
    int t = blockIdx.x, b = blockIdx.z;
    int it = (int)((sqrtf(8.f * t + 1.f) - 1.f) * 0.5f);
    while ((it + 1) * (it + 2) / 2 <= t) ++it;
    while (it * (it + 1) / 2 > t) --it;
    int jt = t - it * (it + 1) / 2;               // jt <= it
    int i0 = it * 128, j0 = jt * 128;
    float* out = SF + (size_t)b * T_ * T_;

    floatx4 acc[4][2];
#pragma unroll
    for (int i = 0; i < 4; ++i)
#pragma unroll
        for (int j = 0; j < 2; ++j) acc[i][j] = (floatx4){0.f, 0.f, 0.f, 0.f};
    size_t arow = ((size_t)b * T_ + i0) * C_;
    size_t brow = ((size_t)b * T_ + j0) * C_;
    gemm_loop8<true>((const char*)(q_hi + arow), (const char*)(q_lo + arow),
                     (const char*)(kw_hi + brow), (const char*)(kw_lo + brow),
                     lds, acc);

    int tid = threadIdx.x, lane = tid & 63, wave = tid >> 6;
    int l15 = lane & 15, quad = lane >> 4;
    int wr = wave >> 2, wc = wave & 3;
    float colsum[2] = {0.f, 0.f};
#pragma unroll
    for (int ni = 0; ni < 2; ++ni) {
        int j = j0 + wc * 32 + ni * 16 + l15;
#pragma unroll
        for (int mi = 0; mi < 4; ++mi)
#pragma unroll
            for (int r = 0; r < 4; ++r) {
                int i = i0 + wr * 64 + mi * 16 + quad * 4 + r;
                float s = acc[mi][ni][r];
                s = (j >= 1 && j < i) ? fmaxf(s, 0.f) : 0.f;
                out[(size_t)i * T_ + j] = s;
                colsum[ni] += s;
            }
    }
#pragma unroll
    for (int ni = 0; ni < 2; ++ni) {
        colsum[ni] += __shfl_xor(colsum[ni], 16);
        colsum[ni] += __shfl_xor(colsum[ni], 32);
    }
    float* red = (float*)lds;                     // [wr][128] (phase-0 area)
    if (quad == 0) {
#pragma unroll
        for (int ni = 0; ni < 2; ++ni)
            red[wr * 128 + wc * 32 + ni * 16 + l15] = colsum[ni];
    }
    __syncthreads();
    if (tid < 128) {
        float ssum = red[tid] + red[128 + tid];
        segsum[((size_t)b * SEG_ + it) * T_ + j0 + tid] = ssum;
    }
}

// ---------------------------------------------------------------------------
// K4: scan_apply with inline exclusive segment prefix from raw segsum.
// ---------------------------------------------------------------------------
__global__ __launch_bounds__(256) void scan_apply(
    float* __restrict__ SF, const float* __restrict__ segsum)
{
    int gid  = blockIdx.x * 256 + threadIdx.x;
    int j    = gid & (T_ - 1);
    int rest = gid >> 11;
    int seg  = rest & (SEG_ - 1);
    int b    = rest >> 4;
    if (seg * SEGLEN_ + SEGLEN_ - 1 < j) return;
    float run = 0.f;
    for (int s = 0; s < seg; ++s) {
        float v = (s * SEGLEN_ + SEGLEN_ - 1 <= j) ? 0.f
                : segsum[((size_t)b * SEG_ + s) * T_ + j];
        run += v;
    }
    float* col = SF + (size_t)b * T_ * T_ + (size_t)(seg * SEGLEN_) * T_ + j;
#pragma unroll 4
    for (int i = 0; i < SEGLEN_; ++i) {
        float s = col[(size_t)i * T_];
        s = (seg * SEGLEN_ + i > j) ? s : 0.f;
        col[(size_t)i * T_] = run;
        run += s;
    }
}

// ---------------------------------------------------------------------------
// K6 (v11): KVBLK=128 flash attention (best-measured attn config, 55.2us).
// ---------------------------------------------------------------------------
__global__ __launch_bounds__(256) void attn_kernel(
    const bf16_t* __restrict__ q_b, const bf16_t* __restrict__ k_b,
    const bf16_t* __restrict__ vt_g, const float* __restrict__ FF,
    bf16_t* __restrict__ y_b, float* __restrict__ opart,
    float* __restrict__ lpart)
{
    extern __shared__ __align__(16) char lds[];
    char* KL = lds;                               // [2][16384]
    char* VL = lds + 32768;                       // [2][16384]
    bf16_t* PBall = (bf16_t*)(lds + 65536);       // [4][2048] per-wave P

    int tid = threadIdx.x, lane = tid & 63, wave = tid >> 6;
    int l15 = lane & 15, quad = lane >> 4;
    int u = blockIdx.x & 15, g = blockIdx.x >> 4;
    int tile, jlo, jhi, half;
    bool split;
    if (g == 0)      { tile = 16 + u; jlo = 0; jhi = 7;                   half = 0; split = true;  }
    else if (g == 1) { tile = u;      jlo = 0; jhi = ((u + 2) >> 1) - 1;  half = 0; split = false; }
    else             { tile = 31 - u; jlo = 8; jhi = ((33 - u) >> 1) - 1; half = 1; split = true;  }
    int h = blockIdx.y, b = blockIdx.z;
    int i0w = tile * 64 + wave * 16;
    const floatx4 fzero = {0.f, 0.f, 0.f, 0.f};

    const bf16_t* qrow = q_b + ((size_t)b * T_ + i0w + l15) * C_ + h * HD_;
    bf16x8 qa0 = *(const bf16x8*)(qrow + quad * 8);
    bf16x8 qa1 = *(const bf16x8*)(qrow + 32 + quad * 8);

    const bf16_t* kbase = k_b + (size_t)b * T_ * C_ + h * HD_;
    const bf16_t* vbase = vt_g + (size_t)(b * H_ + h) * HD_ * T_;
    // C-layout FF row pointers: row = i0w + quad*4 + r, col = j + l15
    const float* fpr[4];
#pragma unroll
    for (int r = 0; r < 4; ++r)
        fpr[r] = FF + ((size_t)b * T_ + i0w + quad * 4 + r) * T_ + jlo * 128 + l15;

    auto stage = [&](int ph, int j0) {
#pragma unroll
        for (int i = 0; i < 4; ++i) {
            int p = (wave * 4 + i) * 64 + lane;
            int r = p >> 3, sp = p & 7, s = sp ^ (r & 7);
            async_copy16(kbase + (size_t)(j0 + r) * C_ + s * 8,
                         KL + ph * 16384 + p * 16);
        }
#pragma unroll
        for (int i = 0; i < 4; ++i) {
            int p = (wave * 4 + i) * 64 + lane;
            int r = p >> 4, sp = p & 15;
            int s = (sp & 8) | ((sp & 7) ^ (r & 7));
            async_copy16(vbase + (size_t)r * T_ + j0 + s * 8,
                         VL + ph * 16384 + p * 16);
        }
    };

    float l_lane[4] = {0.f, 0.f, 0.f, 0.f};
    floatx4 O[4];
#pragma unroll
    for (int nt = 0; nt < 4; ++nt) O[nt] = fzero;

    stage(0, jlo * 128);
    int ph = 0;
#pragma unroll 1
    for (int jc = jlo; jc <= jhi; ++jc) {
        __syncthreads();
        if (jc < jhi) stage(ph ^ 1, (jc + 1) * 128);

        // FF C-layout: 32 dword loads (4 rows x 8 col-subtiles)
        float ff[8][4];
#pragma unroll
        for (int r = 0; r < 4; ++r) {
#pragma unroll
            for (int s = 0; s < 8; ++s) ff[s][r] = fpr[r][s * 16];
            fpr[r] += 128;
        }
        // QK^T -> C-layout (8 col-subtiles of 16)
        const char* KLp = KL + ph * 16384;
        floatx4 pc[8];
#pragma unroll
        for (int s = 0; s < 8; ++s) {
            int r = s * 16 + l15;                 // K row 0..127
            bf16x8 k0 = *(const bf16x8*)&KLp[r * 128 + ((quad     ^ (r & 7)) * 16)];
            bf16x8 k1 = *(const bf16x8*)&KLp[r * 128 + (((quad+4) ^ (r & 7)) * 16)];
            floatx4 p = mfma_bf16(qa0, k0, fzero);
            pc[s] = mfma_bf16(qa1, k1, p);
        }
        // p = exp(qk - ff - 20), elementwise; mask only in diagonal chunk
        bool diag = (jc * 128 + 127 > i0w);
        float p[8][4];
#pragma unroll
        for (int s = 0; s < 8; ++s)
#pragma unroll
            for (int r = 0; r < 4; ++r) {
                float lg = pc[s][r] - ff[s][r] - 20.f;
                if (diag) {
                    int i = i0w + quad * 4 + r;
                    int j = jc * 128 + s * 16 + l15;
                    lg = (j <= i) ? lg : -__builtin_inff();
                }
                p[s][r] = __expf(lg);
            }
#pragma unroll
        for (int r = 0; r < 4; ++r)
            l_lane[r] += ((p[0][r] + p[1][r]) + (p[2][r] + p[3][r]))
                       + ((p[4][r] + p[5][r]) + (p[6][r] + p[7][r]));

        // P: C-layout -> bf16 per-wave LDS (16B-chunk XOR swizzle on low 3
        // bits of the 16-chunk index) -> A-frags
        bf16_t* Pw = PBall + wave * 2048;
#pragma unroll
        for (int s = 0; s < 8; ++s)
#pragma unroll
            for (int r = 0; r < 4; ++r) {
                int rr = quad * 4 + r;
                int c  = s * 2 + (l15 >> 3);
                int ch = (c & 8) | ((c & 7) ^ (rr & 7));
                Pw[rr * 128 + ch * 8 + (l15 & 7)] = (bf16_t)p[s][r];
            }
        asm volatile("s_waitcnt lgkmcnt(0)" ::: "memory");
        int xk = l15 & 7;
        bf16x8 pa[4];
#pragma unroll
        for (int gk = 0; gk < 4; ++gk) {
            int c  = gk * 4 + quad;
            int ch = (c & 8) | ((c & 7) ^ xk);
            pa[gk] = *(const bf16x8*)&Pw[l15 * 128 + ch * 8];
        }
        const char* VLp = VL + ph * 16384;
#pragma unroll
        for (int nt = 0; nt < 4; ++nt) {
            int rv = nt * 16 + l15;               // V^T row (hd dim)
#pragma unroll
            for (int gk = 0; gk < 4; ++gk) {
                int c  = gk * 4 + quad;
                int ch = (c & 8) | ((c & 7) ^ (rv & 7));
                bf16x8 v = *(const bf16x8*)&VLp[rv * 256 + ch * 16];
                O[nt] = mfma_bf16(pa[gk], v, O[nt]);
            }
        }
        ph ^= 1;
    }

    // deferred l reduction across the 16 l15-lanes of each quad
#pragma unroll
    for (int r = 0; r < 4; ++r)
#pragma unroll
        for (int d = 1; d < 16; d <<= 1)
            l_lane[r] += __shfl_xor(l_lane[r], d);

    if (!split) {
#pragma unroll
        for (int r = 0; r < 4; ++r) {
            float inv = 1.f / l_lane[r];
            int i = i0w + quad * 4 + r;
#pragma unroll
            for (int nt = 0; nt < 4; ++nt)
                y_b[((size_t)b * T_ + i) * C_ + h * HD_ + nt * 16 + l15] =
                    (bf16_t)(O[nt][r] * inv);
        }
    } else {
        size_t ob = ((((size_t)(b * H_ + h) * 16 + (tile - 16)) * 2 + half) * 4096);
#pragma unroll
        for (int r = 0; r < 4; ++r) {
            int rl = wave * 16 + quad * 4 + r;   // row within the 64-row tile
#pragma unroll
            for (int nt = 0; nt < 4; ++nt)
                opart[ob + (size_t)rl * 64 + nt * 16 + l15] = O[nt][r];
        }
        if (l15 == 0) {
            size_t lb = (((size_t)(b * H_ + h) * 16 + (tile - 16)) * 2 + half) * 64;
#pragma unroll
            for (int r = 0; r < 4; ++r)
                lpart[lb + wave * 16 + quad * 4 + r] = l_lane[r];
        }
    }
}

// ---------------------------------------------------------------------------
// K6b: merge split-tile partials: y = (O0+O1)/(l0+l1).
// ---------------------------------------------------------------------------
__global__ __launch_bounds__(256) void merge_kernel(
    const float* __restrict__ opart, const float* __restrict__ lpart,
    bf16_t* __restrict__ y_b)
{
    int tt = blockIdx.x, h = blockIdx.y, b = blockIdx.z;
    size_t b0 = (((size_t)(b * H_ + h) * 16 + tt) * 2) * 4096;
    size_t l0 = (((size_t)(b * H_ + h) * 16 + tt) * 2) * 64;
    int tile = 16 + tt;
#pragma unroll 4
    for (int e = threadIdx.x; e < 4096; e += 256) {
        int row = e >> 6, col = e & 63;
        float l = lpart[l0 + row] + lpart[l0 + 64 + row];
        float o = opart[b0 + e] + opart[b0 + 4096 + e];
        y_b[((size_t)b * T_ + tile * 64 + row) * C_ + h * HD_ + col] =
            (bf16_t)(o / l);
    }
}

// ---------------------------------------------------------------------------
// K7: out = y @ w_proj^T + b_proj  (512 threads, dbuf 32 KB)
// ---------------------------------------------------------------------------
__global__ __launch_bounds__(512) void proj_gemm(
    const bf16_t* __restrict__ y_b, const bf16_t* __restrict__ wp_b,
    const float* __restrict__ bias, float* __restrict__ out)
{
    extern __shared__ char lds[];
    int m0 = blockIdx.x * 128, n0 = blockIdx.y * 128;
    floatx4 acc[4][2];
#pragma unroll
    for (int i = 0; i < 4; ++i)
#pragma unroll
        for (int j = 0; j < 2; ++j) acc[i][j] = (floatx4){0.f, 0.f, 0.f, 0.f};
    gemm_loop8<false>((const char*)(y_b + (size_t)m0 * C_), nullptr,
                      (const char*)(wp_b + (size_t)n0 * C_), nullptr, lds, acc);

    int tid = threadIdx.x, lane = tid & 63, wave = tid >> 6;
    int l15 = lane & 15, quad = lane >> 4;
    int wr = wave >> 2, wc = wave & 3;
#pragma unroll
    for (int ni = 0; ni < 2; ++ni) {
        int col = n0 + wc * 32 + ni * 16 + l15;
        float bb = bias[col];
#pragma unroll
        for (int mi = 0; mi < 4; ++mi)
#pragma unroll
            for (int r = 0; r < 4; ++r)
                out[(size_t)(m0 + wr * 64 + mi * 16 + quad * 4 + r) * C_ + col] =
                    acc[mi][ni][r] + bb;
    }
}

// ---------------------------------------------------------------------------
extern "C" void kernel_launch(void* const* d_in, const int* in_sizes, int n_in,
                              void* d_out, int out_size, void* d_ws, size_t ws_size,
                              hipStream_t stream)
{
    const float* x      = (const float*)d_in[0];
    const float* w_attn = (const float*)d_in[1];
    const float* b_attn = (const float*)d_in[2];
    const float* w_proj = (const float*)d_in[3];
    const float* b_proj = (const float*)d_in[4];
    const float* sel_w  = (const float*)d_in[5];
    float* out = (float*)d_out;

    char* ws = (char*)d_ws;
    size_t off = 0;
    auto alloc = [&](size_t bytes) {
        void* p = ws + off;
        off += (bytes + 255) & ~(size_t)255;
        return p;
    };
    const size_t MC2 = (size_t)M_ * C_ * 2;          // 6.29 MB
    // Live-through-attn region
    bf16_t* q_hi   = (bf16_t*)alloc(MC2);
    bf16_t* kw_hi  = (bf16_t*)alloc(MC2);
    bf16_t* k_b    = (bf16_t*)alloc(MC2);
    bf16_t* y_b    = (bf16_t*)alloc(MC2);
    bf16_t* wp_b   = (bf16_t*)alloc((size_t)C_ * C_ * 2);
    float*  segsum = (float*)alloc((size_t)B_ * SEG_ * T_ * 4);
    float*  lpart  = (float*)alloc((size_t)B_ * H_ * 16 * 2 * 64 * 4);  // 0.2 MB
    // Dead-by-attn group: q_lo, kw_lo (12.58 MB, dead after s_gemm) are
    // aliased by opart (12.58 MB).  vt (written by qkv, read by attn)
    // lives in the third slot, disjoint from opart.
    char* dead_base = (char*)alloc(3 * MC2);
    bf16_t* q_lo  = (bf16_t*)dead_base;
    bf16_t* kw_lo = (bf16_t*)(dead_base + MC2);
    bf16_t* vt    = (bf16_t*)(dead_base + 2 * MC2);
    float*  opart = (float*)dead_base;
    // Aliased region: phase-1 splits and SF never live simultaneously
    char* shared_base = (char*)alloc((size_t)B_ * T_ * T_ * 4);   // 33.55 MB
    bf16_t* x_hi = (bf16_t*)shared_base;
    bf16_t* x_lo = (bf16_t*)(shared_base + MC2);
    bf16_t* w_hi = (bf16_t*)(shared_base + 2 * MC2);
    bf16_t* w_lo = (bf16_t*)(shared_base + 2 * MC2 + (size_t)N3_ * C_ * 2);
    float*  SF   = (float*)shared_base;

    int nx = M_ * C_, nw = N3_ * C_, np = C_ * C_;
    int ntot4 = (nx + nw + np) / 4;
    prep_kernel<<<dim3((ntot4 + 255) / 256), 256, 0, stream>>>(
        x, w_attn, w_proj, x_hi, x_lo, w_hi, w_lo, wp_b, nx / 4, nw / 4, np / 4);

    qkv_gemm<<<dim3(M_ / 128, N3_ / 128), 512, 65536, stream>>>(
        x_hi, x_lo, w_hi, w_lo, b_attn, sel_w,
        q_hi, q_lo, kw_hi, kw_lo, k_b, vt);
    s_gemm<<<dim3(136, 1, B_), 512, 65536, stream>>>(
        q_hi, q_lo, kw_hi, kw_lo, SF, segsum);
    scan_apply<<<dim3(B_ * SEG_ * T_ / 256), 256, 0, stream>>>(SF, segsum);
    attn_kernel<<<dim3(48, H_, B_), 256, 81920, stream>>>(
        q_hi, k_b, vt, SF, y_b, opart, lpart);
    merge_kernel<<<dim3(16, H_, B_), 256, 0, stream>>>(opart, lpart, y_b);
    proj_gemm<<<dim3(M_ / 128, C_ / 128), 512, 32768, stream>>>(y_b, wp_b, b_proj, out);
}